// Round 12
// baseline (118.794 us; speedup 1.0000x reference)
//
#include <hip/hip_runtime.h>

// N=65536 nodes, D=64 feat, K=32 topk, E=N*16 edges (sorted edge_dst).
// Round-12 (post-mortem R11: WIN 124.5->116.7; agg ~22us at ~6.1 TB/s
// effective L2/L3 gather = near structural floor; top-5 all harness fills).
//  prep change: 1-deep software pipeline — prefetch next trip's topk pair
//  while the current trip's LDS zero->ds_add->read->pack chain runs; and
//  part A gets edge_dst[e-1] via __shfl_up instead of a 2nd global load.
//  agg unchanged from R11 (decoupled coalesced src prefetch + 16
//  independent 128B row gathers per slot, in-register completion).

#define DFEAT 64
#define KTOP  32

__device__ __forceinline__ unsigned short f2bf(float x) {
    unsigned u = __float_as_uint(x);
    u += 0x7fffu + ((u >> 16) & 1u);               // round-to-nearest-even
    return (unsigned short)(u >> 16);
}
__device__ __forceinline__ float bfu(unsigned int u16) {
    return __uint_as_float(u16 << 16);
}

__global__ __launch_bounds__(256) void prep_kernel(
    const float* __restrict__ topk_v,
    const int*   __restrict__ topk_i,
    const int*   __restrict__ edge_dst,
    unsigned int* __restrict__ dense16,   // 32 words (64 bf16) per node
    int*          __restrict__ indptr,
    int n_nodes, int n_edges)
{
    __shared__ float rows[4][2 * DFEAT];  // wave-private 2-node rows
    int tid    = blockIdx.x * blockDim.x + threadIdx.x;
    int stride = gridDim.x * blockDim.x;
    int lane   = threadIdx.x & 63;
    int wid    = threadIdx.x >> 6;
    int wave   = tid >> 6;
    int nwaves = stride >> 6;
    int half   = lane >> 5;

    // Part A: indptr[node] = first edge with dst >= node; indptr[n]=E.
    // prev comes from the neighbor lane (consecutive e per lane); only
    // lane 0 of the wave does the extra global load.
    for (int e = tid; e < n_edges; e += stride) {
        int cur  = edge_dst[e];
        int prev = __shfl_up(cur, 1, 64);
        if (lane == 0) prev = (e == 0) ? -1 : edge_dst[e - 1];
        for (int node = prev + 1; node <= cur; ++node) indptr[node] = e;
        if (e == n_edges - 1) {
            for (int node = cur + 1; node <= n_nodes; ++node) indptr[node] = n_edges;
        }
    }

    // Part B: bf16 dense rows, 2 nodes per wave trip, no block barriers,
    // 1-deep software pipeline on the topk loads.
    int total_pairs = n_nodes >> 1;
    int pair = wave;
    int   idx = 0;
    float val = 0.0f;
    if (pair < total_pairs) {
        size_t base = (size_t)(pair * 2) * KTOP;
        idx = topk_i[base + lane];
        val = topk_v[base + lane];
    }
    for (; pair < total_pairs; pair += nwaves) {
        int nxt = pair + nwaves;
        int   nidx = 0;
        float nval = 0.0f;
        if (nxt < total_pairs) {                   // prefetch next trip
            size_t nbase = (size_t)(nxt * 2) * KTOP;
            nidx = topk_i[nbase + lane];
            nval = topk_v[nbase + lane];
        }

        int nodeA = pair * 2;
        rows[wid][lane]      = 0.0f;
        rows[wid][lane + 64] = 0.0f;
        atomicAdd(&rows[wid][half * DFEAT + idx], val);   // ds_add, dup-safe
        float a = rows[wid][2 * lane];
        float b = rows[wid][2 * lane + 1];
        dense16[nodeA * 32 + lane] =
            (unsigned int)f2bf(a) | ((unsigned int)f2bf(b) << 16);

        idx = nidx;
        val = nval;
    }
}

// Aggregate: lane = slot(0..7)*8 + f(0..7); slot s of wave w owns node
// w*8+s. Lane holds bf16 features [8f, 8f+8) of its node's row.
__global__ __launch_bounds__(256) void aggregate_bf16_kernel(
    const uint4*  __restrict__ d16q,    // row = 8 x uint4 (64 bf16, 128B)
    const float4* __restrict__ feat4,
    const float*  __restrict__ eps,
    const int*    __restrict__ edge_src,
    const int*    __restrict__ indptr,
    float4*       __restrict__ out4,
    int n_nodes)
{
    int lane = threadIdx.x & 63;
    int f    = lane & 7;     // feature octet / lane-in-slot
    int slot = lane >> 3;    // node slot within wave
    int wave = (blockIdx.x * blockDim.x + threadIdx.x) >> 6;
    int node = wave * 8 + slot;
    if (node >= n_nodes) return;

    float sc = 1.0f + eps[0];
    int s = indptr[node];
    int e = indptr[node + 1];

    float acc[8] = {0, 0, 0, 0, 0, 0, 0, 0};
    for (int base = s; base < e; base += 16) {
        // Phase A: coalesced src prefetch — slot's lanes grab 16 edges.
        int i0 = base + f;
        int i1 = base + 8 + f;
        int src0 = (i0 < e) ? edge_src[i0] : -1;
        int src1 = (i1 < e) ? edge_src[i1] : -1;

        // Phase B: 16 independent row gathers (shfl only distributes the
        // already-loaded index; no load-dependent address chain).
#pragma unroll
        for (int j = 0; j < 16; ++j) {
            int sj = __shfl(j < 8 ? src0 : src1, slot * 8 + (j & 7), 64);
            if (sj >= 0) {
                uint4 r = d16q[(size_t)sj * 8 + f];   // 8 rows per instr
                acc[0] += bfu(r.x & 0xffffu); acc[1] += bfu(r.x >> 16);
                acc[2] += bfu(r.y & 0xffffu); acc[3] += bfu(r.y >> 16);
                acc[4] += bfu(r.z & 0xffffu); acc[5] += bfu(r.z >> 16);
                acc[6] += bfu(r.w & 0xffffu); acc[7] += bfu(r.w >> 16);
            }
        }
    }

    float4 ft0 = feat4[(size_t)node * 16 + 2 * f];
    float4 ft1 = feat4[(size_t)node * 16 + 2 * f + 1];
    float4 o0, o1;
    o0.x = sc * ft0.x + acc[0];
    o0.y = sc * ft0.y + acc[1];
    o0.z = sc * ft0.z + acc[2];
    o0.w = sc * ft0.w + acc[3];
    o1.x = sc * ft1.x + acc[4];
    o1.y = sc * ft1.y + acc[5];
    o1.z = sc * ft1.z + acc[6];
    o1.w = sc * ft1.w + acc[7];
    out4[(size_t)node * 16 + 2 * f]     = o0;
    out4[(size_t)node * 16 + 2 * f + 1] = o1;
}

extern "C" void kernel_launch(void* const* d_in, const int* in_sizes, int n_in,
                              void* d_out, int out_size, void* d_ws, size_t ws_size,
                              hipStream_t stream)
{
    const float* feat     = (const float*)d_in[0];
    const float* topk_v   = (const float*)d_in[1];
    const float* eps      = (const float*)d_in[2];
    const int*   topk_i   = (const int*)d_in[3];
    const int*   edge_src = (const int*)d_in[4];
    const int*   edge_dst = (const int*)d_in[5];
    float*       out      = (float*)d_out;

    int n_nodes = in_sizes[0] / DFEAT;
    int n_edges = in_sizes[4];

    // ws layout: [dense16: n*64*2 B] [indptr: (n+1)*4 B]
    unsigned int* dense16 = (unsigned int*)d_ws;
    size_t d16_bytes = (size_t)n_nodes * DFEAT * sizeof(unsigned short);
    size_t d16_pad   = (d16_bytes + 255) & ~(size_t)255;
    int*   indptr    = (int*)((char*)d_ws + d16_pad);

    prep_kernel<<<2048, 256, 0, stream>>>(topk_v, topk_i, edge_dst,
                                          dense16, indptr, n_nodes, n_edges);

    int agg_waves  = (n_nodes + 7) / 8;              // one 8-node wave each
    int agg_blocks = (agg_waves * 64 + 255) / 256;   // 4 waves per block
    aggregate_bf16_kernel<<<agg_blocks, 256, 0, stream>>>(
        (const uint4*)dense16, (const float4*)feat, eps, edge_src,
        indptr, (float4*)out, n_nodes);
}

// Round 13
// 117.265 us; speedup vs baseline: 1.0130x; 1.0130x over previous
//
#include <hip/hip_runtime.h>

// N=65536 nodes, D=64 feat, K=32 topk, E=N*16 edges (sorted edge_dst).
// FINAL (R11 structure, re-locked after R12's pipeline regressed):
//  1. prep (2048 WGs): CSR indptr boundary-detect + bf16 dense build
//     (wave-private LDS rows, ds_add scatter, no block barriers). ~10us.
//  2. agg: lane = slot(0..7)*8 + feat_octet(0..7); one node per slot
//     (8192 waves x 8 = 65536 nodes, single pass). Per 16-edge chunk:
//     phase A coalesced src prefetch (2 loads/lane), phase B shfl-distribute
//     -> 16 INDEPENDENT 128B row gathers, in-register completion (no fold),
//     direct 2x float4 store. ~22us at ~6.1 TB/s effective L2/L3 gather.
//  Session lessons: cooperative grid.sync ~150us on MI355X (R9); nt hints
//  regress gather-heavy kernels (R10); prep SW-pipeline neutral (R12) —
//  occupancy already hides the LDS-chain latency.

#define DFEAT 64
#define KTOP  32

__device__ __forceinline__ unsigned short f2bf(float x) {
    unsigned u = __float_as_uint(x);
    u += 0x7fffu + ((u >> 16) & 1u);               // round-to-nearest-even
    return (unsigned short)(u >> 16);
}
__device__ __forceinline__ float bfu(unsigned int u16) {
    return __uint_as_float(u16 << 16);
}

__global__ __launch_bounds__(256) void prep_kernel(
    const float* __restrict__ topk_v,
    const int*   __restrict__ topk_i,
    const int*   __restrict__ edge_dst,
    unsigned int* __restrict__ dense16,   // 32 words (64 bf16) per node
    int*          __restrict__ indptr,
    int n_nodes, int n_edges)
{
    __shared__ float rows[4][2 * DFEAT];  // wave-private 2-node rows
    int tid    = blockIdx.x * blockDim.x + threadIdx.x;
    int stride = gridDim.x * blockDim.x;
    int lane   = threadIdx.x & 63;
    int wid    = threadIdx.x >> 6;
    int wave   = tid >> 6;
    int nwaves = stride >> 6;
    int half   = lane >> 5;

    // Part A: indptr[node] = first edge with dst >= node; indptr[n]=E.
    for (int e = tid; e < n_edges; e += stride) {
        int cur  = edge_dst[e];
        int prev = (e == 0) ? -1 : edge_dst[e - 1];
        for (int node = prev + 1; node <= cur; ++node) indptr[node] = e;
        if (e == n_edges - 1) {
            for (int node = cur + 1; node <= n_nodes; ++node) indptr[node] = n_edges;
        }
    }

    // Part B: bf16 dense rows, 2 nodes per wave trip, no block barriers
    // (rows are wave-private; wave DS ops are program-ordered).
    int total_pairs = n_nodes >> 1;
    for (int pair = wave; pair < total_pairs; pair += nwaves) {
        int nodeA = pair * 2;

        rows[wid][lane]      = 0.0f;
        rows[wid][lane + 64] = 0.0f;

        size_t base = (size_t)nodeA * KTOP;       // A's 32 pairs then B's 32
        int   idx = topk_i[base + lane];
        float val = topk_v[base + lane];
        atomicAdd(&rows[wid][half * DFEAT + idx], val);   // ds_add, dup-safe

        float a = rows[wid][2 * lane];
        float b = rows[wid][2 * lane + 1];
        dense16[nodeA * 32 + lane] =
            (unsigned int)f2bf(a) | ((unsigned int)f2bf(b) << 16);
    }
}

// Aggregate: lane = slot(0..7)*8 + f(0..7); slot s of wave w owns node
// w*8+s. Lane holds bf16 features [8f, 8f+8) of its node's row.
__global__ __launch_bounds__(256) void aggregate_bf16_kernel(
    const uint4*  __restrict__ d16q,    // row = 8 x uint4 (64 bf16, 128B)
    const float4* __restrict__ feat4,
    const float*  __restrict__ eps,
    const int*    __restrict__ edge_src,
    const int*    __restrict__ indptr,
    float4*       __restrict__ out4,
    int n_nodes)
{
    int lane = threadIdx.x & 63;
    int f    = lane & 7;     // feature octet / lane-in-slot
    int slot = lane >> 3;    // node slot within wave
    int wave = (blockIdx.x * blockDim.x + threadIdx.x) >> 6;
    int node = wave * 8 + slot;
    if (node >= n_nodes) return;

    float sc = 1.0f + eps[0];
    int s = indptr[node];
    int e = indptr[node + 1];

    float acc[8] = {0, 0, 0, 0, 0, 0, 0, 0};
    for (int base = s; base < e; base += 16) {
        // Phase A: coalesced src prefetch — slot's lanes grab 16 edges.
        int i0 = base + f;
        int i1 = base + 8 + f;
        int src0 = (i0 < e) ? edge_src[i0] : -1;
        int src1 = (i1 < e) ? edge_src[i1] : -1;

        // Phase B: 16 independent row gathers (shfl only distributes the
        // already-loaded index; no load-dependent address chain).
#pragma unroll
        for (int j = 0; j < 16; ++j) {
            int sj = __shfl(j < 8 ? src0 : src1, slot * 8 + (j & 7), 64);
            if (sj >= 0) {
                uint4 r = d16q[(size_t)sj * 8 + f];   // 8 rows per instr
                acc[0] += bfu(r.x & 0xffffu); acc[1] += bfu(r.x >> 16);
                acc[2] += bfu(r.y & 0xffffu); acc[3] += bfu(r.y >> 16);
                acc[4] += bfu(r.z & 0xffffu); acc[5] += bfu(r.z >> 16);
                acc[6] += bfu(r.w & 0xffffu); acc[7] += bfu(r.w >> 16);
            }
        }
    }

    float4 ft0 = feat4[(size_t)node * 16 + 2 * f];
    float4 ft1 = feat4[(size_t)node * 16 + 2 * f + 1];
    float4 o0, o1;
    o0.x = sc * ft0.x + acc[0];
    o0.y = sc * ft0.y + acc[1];
    o0.z = sc * ft0.z + acc[2];
    o0.w = sc * ft0.w + acc[3];
    o1.x = sc * ft1.x + acc[4];
    o1.y = sc * ft1.y + acc[5];
    o1.z = sc * ft1.z + acc[6];
    o1.w = sc * ft1.w + acc[7];
    out4[(size_t)node * 16 + 2 * f]     = o0;
    out4[(size_t)node * 16 + 2 * f + 1] = o1;
}

extern "C" void kernel_launch(void* const* d_in, const int* in_sizes, int n_in,
                              void* d_out, int out_size, void* d_ws, size_t ws_size,
                              hipStream_t stream)
{
    const float* feat     = (const float*)d_in[0];
    const float* topk_v   = (const float*)d_in[1];
    const float* eps      = (const float*)d_in[2];
    const int*   topk_i   = (const int*)d_in[3];
    const int*   edge_src = (const int*)d_in[4];
    const int*   edge_dst = (const int*)d_in[5];
    float*       out      = (float*)d_out;

    int n_nodes = in_sizes[0] / DFEAT;
    int n_edges = in_sizes[4];

    // ws layout: [dense16: n*64*2 B] [indptr: (n+1)*4 B]
    unsigned int* dense16 = (unsigned int*)d_ws;
    size_t d16_bytes = (size_t)n_nodes * DFEAT * sizeof(unsigned short);
    size_t d16_pad   = (d16_bytes + 255) & ~(size_t)255;
    int*   indptr    = (int*)((char*)d_ws + d16_pad);

    prep_kernel<<<2048, 256, 0, stream>>>(topk_v, topk_i, edge_dst,
                                          dense16, indptr, n_nodes, n_edges);

    int agg_waves  = (n_nodes + 7) / 8;              // one 8-node wave each
    int agg_blocks = (agg_waves * 64 + 255) / 256;   // 4 waves per block
    aggregate_bf16_kernel<<<agg_blocks, 256, 0, stream>>>(
        (const uint4*)dense16, (const float4*)feat, eps, edge_src,
        indptr, (float4*)out, n_nodes);
}